// Round 5
// baseline (199.134 us; speedup 1.0000x reference)
//
#include <hip/hip_runtime.h>
#include <stdint.h>

// LUTLayer forward, MI355X (gfx950).
// x: (2048, 4096) f32 in {0,1}; mapping: (4096, 6) i32; luts: (4096, 64) f32.
// out[b][j] = (luts[j][ sum_k x[b][mapping[j][k]] << k ] > 0) ? 1.0f : 0.0f
//
// R6 == R5 with the fence spelling fixed (__hip_atomic_fence doesn't exist;
// use __builtin_amdgcn_fence(__ATOMIC_ACQUIRE, "agent")).
// ONE dispatch. 512 blocks x 256 threads (2/CU, fully schedulable).
// Block b (gp = b>>3 is BOTH its produced and consumed row-group; cb=b&7):
//  P: pack 32 rows x 512 cols (cols cb*512..) -> global xbits[gp], fence,
//     flag[b] = MAGIC (release, agent scope).
//  L: lut sign masks for own 512 cols via wave ballots -> LDS smask (hides wait).
//  C: t0 spins on own group's 8 flags (contiguous sibling blocks b&~7..b|7 ->
//     deadlock-free for any schedule; flags monotonic), acquire fence, load
//     16 KB image -> LDS, then 12 random LDS gathers/thread (R=32 amortization:
//     0.1875 gathers/output -- R4's R=4 was 1.5/output and LDS-pipe-bound),
//     32 rows x 2 cols pure VALU, nontemporal float2 stores.
// MAGIC is a non-repeated-32-bit pattern: fillBufferAligned poison can't alias.
// xbits is iteration-invariant (same x), so even stale caches are value-correct;
// agent-scope release/acquire covers the first iteration.
// Traffic: 33.5 x + 33.5 out + ~1 luts + 1 xbits rt + 0.1 mapping ~= 70 MB
// => 11.1 us floor; saves 2 launches + lutprep serialization vs R1's 15 us.

static constexpr int IN    = 4096;
static constexpr int OUTW  = 4096;
static constexpr int BATCH = 2048;
static constexpr unsigned long long MAGIC = 0x9E3779B97F4A7C15ULL;

typedef float vfloat2 __attribute__((ext_vector_type(2)));

__global__ __launch_bounds__(256, 2) void lut_fused_kernel(const float* __restrict__ x,
                                                           const int* __restrict__ mapping,
                                                           const float* __restrict__ luts,
                                                           unsigned long long* __restrict__ flags,
                                                           uint32_t* __restrict__ xbits,
                                                           float* __restrict__ out) {
    __shared__ uint32_t sbits[IN];                 // 16 KB bit image of group gp
    __shared__ unsigned long long smask[512];      // 4 KB lut sign masks, own cols

    const int b  = blockIdx.x;
    const int t  = threadIdx.x;
    const int gp = b >> 3;                         // row-group 0..63 (produce==consume)
    const int cb = b & 7;                          // col chunk/block 0..7 (512 cols)

    // ---- Phase P: pack 32 rows x 512 cols into global xbits ----
    {
        const int m0 = cb * 512 + t * 2;           // 2 cols per thread
        const float* xb = x + ((size_t)gp * 32) * IN + m0;
        uint32_t v0 = 0, v1 = 0;
#pragma unroll
        for (int r = 0; r < 32; ++r) {
            const vfloat2 f = __builtin_nontemporal_load((const vfloat2*)(xb + (size_t)r * IN));
            v0 |= ((uint32_t)(f.x != 0.0f)) << r;
            v1 |= ((uint32_t)(f.y != 0.0f)) << r;
        }
        *(uint2*)(xbits + (size_t)gp * IN + m0) = make_uint2(v0, v1);
    }
    __threadfence();                               // device-scope: publish my stores
    __syncthreads();                               // all threads' stores fenced
    if (t == 0) {
        __hip_atomic_store(&flags[b], MAGIC, __ATOMIC_RELEASE, __HIP_MEMORY_SCOPE_AGENT);
    }

    // ---- Phase L: lut sign masks for my 512 cols (hides sibling wait) ----
    {
        const int wv = t >> 6, ln = t & 63;
        const int colbase = cb * 512 + wv * 128;   // global col of this wave's first
        const float* lp = luts + (size_t)colbase * 64 + ln;
#pragma unroll
        for (int i = 0; i < 128; i += 4) {
            const float v0 = lp[(size_t)(i + 0) * 64];
            const float v1 = lp[(size_t)(i + 1) * 64];
            const float v2 = lp[(size_t)(i + 2) * 64];
            const float v3 = lp[(size_t)(i + 3) * 64];
            const unsigned long long m0 = __ballot(v0 > 0.0f);
            const unsigned long long m1 = __ballot(v1 > 0.0f);
            const unsigned long long m2 = __ballot(v2 > 0.0f);
            const unsigned long long m3 = __ballot(v3 > 0.0f);
            if (ln == 0) {
                smask[wv * 128 + i + 0] = m0;
                smask[wv * 128 + i + 1] = m1;
                smask[wv * 128 + i + 2] = m2;
                smask[wv * 128 + i + 3] = m3;
            }
        }
    }

    // ---- Phase C: wait for siblings, load image, compute ----
    const int jloc = t * 2;                        // local col 0..510
    const int j    = cb * 512 + jloc;              // global output col
    const int4* mrow = (const int4*)(mapping + (size_t)j * 6);  // prefetch pre-spin
    const int4 q0 = mrow[0];   // c0: k0..k3
    const int4 q1 = mrow[1];   // c0: k4,k5 ; c1: k0,k1
    const int4 q2 = mrow[2];   // c1: k2..k5

    if (t == 0) {
        const unsigned long long* f = flags + (size_t)gp * 8;
        for (;;) {
            int ok = 0;
#pragma unroll
            for (int c = 0; c < 8; ++c)
                ok += (__hip_atomic_load(&f[c], __ATOMIC_ACQUIRE, __HIP_MEMORY_SCOPE_AGENT) == MAGIC);
            if (ok == 8) break;
            __builtin_amdgcn_s_sleep(2);
        }
    }
    __syncthreads();
    __builtin_amdgcn_fence(__ATOMIC_ACQUIRE, "agent");  // invalidate stale lines

    {
        const uint4* src = (const uint4*)(xbits + (size_t)gp * IN);
        uint4* dst = (uint4*)sbits;
#pragma unroll
        for (int i = 0; i < 4; ++i) dst[t + i * 256] = src[t + i * 256];
    }
    __syncthreads();

    const uint32_t w00 = sbits[q0.x], w01 = sbits[q0.y], w02 = sbits[q0.z],
                   w03 = sbits[q0.w], w04 = sbits[q1.x], w05 = sbits[q1.y];
    const uint32_t w10 = sbits[q1.z], w11 = sbits[q1.w], w12 = sbits[q2.x],
                   w13 = sbits[q2.y], w14 = sbits[q2.z], w15 = sbits[q2.w];
    const unsigned long long mk0 = smask[jloc];
    const unsigned long long mk1 = smask[jloc + 1];

    float* outp = out + ((size_t)gp * 32) * OUTW + j;
#pragma unroll
    for (int r = 0; r < 32; ++r) {
        const uint32_t a0 = ((w00 >> r) & 1u)        | (((w01 >> r) & 1u) << 1)
                          | (((w02 >> r) & 1u) << 2) | (((w03 >> r) & 1u) << 3)
                          | (((w04 >> r) & 1u) << 4) | (((w05 >> r) & 1u) << 5);
        const uint32_t a1 = ((w10 >> r) & 1u)        | (((w11 >> r) & 1u) << 1)
                          | (((w12 >> r) & 1u) << 2) | (((w13 >> r) & 1u) << 3)
                          | (((w14 >> r) & 1u) << 4) | (((w15 >> r) & 1u) << 5);
        vfloat2 res;
        res.x = (float)((uint32_t)(mk0 >> a0) & 1u);
        res.y = (float)((uint32_t)(mk1 >> a1) & 1u);
        __builtin_nontemporal_store(res, (vfloat2*)(outp + (size_t)r * OUTW));
    }
}

// Fallback if workspace is too small: direct per-output computation.
__global__ __launch_bounds__(256) void naive_kernel(const float* __restrict__ x,
                                                    const int* __restrict__ mapping,
                                                    const float* __restrict__ luts,
                                                    float* __restrict__ out) {
    const int idx = blockIdx.x * 256 + threadIdx.x;
    if (idx >= BATCH * OUTW) return;
    const int b = idx >> 12;
    const int j = idx & (OUTW - 1);
    const float* xr = x + (size_t)b * IN;
    int addr = 0;
#pragma unroll
    for (int k = 0; k < 6; ++k) {
        addr |= ((int)(xr[mapping[j * 6 + k]] != 0.0f)) << k;
    }
    out[idx] = (luts[j * 64 + addr] > 0.0f) ? 1.0f : 0.0f;
}

extern "C" void kernel_launch(void* const* d_in, const int* in_sizes, int n_in,
                              void* d_out, int out_size, void* d_ws, size_t ws_size,
                              hipStream_t stream) {
    const float* x       = (const float*)d_in[0];
    const int*   mapping = (const int*)d_in[1];
    const float* luts    = (const float*)d_in[2];
    float* out = (float*)d_out;

    const size_t flags_bytes = 512 * 8;                 // 4 KB
    const size_t xbits_bytes = (size_t)64 * IN * 4;     // 1 MB
    if (ws_size >= flags_bytes + xbits_bytes) {
        unsigned long long* flags = (unsigned long long*)d_ws;
        uint32_t* xbits = (uint32_t*)((char*)d_ws + flags_bytes);
        hipLaunchKernelGGL(lut_fused_kernel, dim3(512), dim3(256), 0, stream,
                           x, mapping, luts, flags, xbits, out);
    } else {
        hipLaunchKernelGGL(naive_kernel, dim3((BATCH * OUTW) / 256), dim3(256), 0, stream,
                           x, mapping, luts, out);
    }
}

// Round 6
// 91.034 us; speedup vs baseline: 2.1875x; 2.1875x over previous
//
#include <hip/hip_runtime.h>
#include <stdint.h>

// LUTLayer forward, MI355X (gfx950).
// x: (2048, 4096) f32 in {0,1}; mapping: (4096, 6) i32; luts: (4096, 64) f32.
// out[b][j] = (luts[j][ sum_k x[b][mapping[j][k]] << k ] > 0) ? 1.0f : 0.0f
//
// R7: restore the R1 champion (measured 91.4 us, absmax 0). Session findings:
//  - R2 (fused, 4x x re-read, XCD-L2 dedup bet): +8 us. L2 dedup didn't happen.
//  - R4 (read-once, 4-row groups): +7 us. 1.5 LDS gathers/output vs 0.1875 here;
//    LDS-pipe-bound after the sync. Row-group=32 amortization is essential.
//  - R6 (single dispatch, cross-block flag sync): +108 us. Agent-scope
//    release/acquire + threadfence + sc1 spin loads cost ~110 us -- cross-XCD
//    coherence machinery is 40x the launch gap it saves (Guideline 16).
// Structural floor: 67 MB compulsory HBM traffic ~= 10.6 us; two-dispatch adds
// only launch gap + ramps (~2-3 us). Measured controllable share: ~15 us of the
// 91.4; the remaining ~76.5 us is harness workspace-poison fills (43 us each at
// 77% HBM peak), outside kernel control.
//
// Structure:
//  Kernel A (288 blocks):
//    blocks [0,256): pack xbits[g][m] (uint32), bit r = (x[g*32+r][m] != 0).
//      Transposed bit-pack => 6 word gathers give addresses for 32 rows at once.
//    blocks [256,288): lut_pos[j] = 64-bit ballot mask of (luts[j][e] > 0).
//      (clip to [-1,1] preserves sign; only sign matters for the output.)
//  Kernel B (512 blocks): block = (row-group g, 512-col block); 16 KB LDS bit
//    image; 12 LDS gathers/thread, then 32 rows x 2 cols pure VALU + float2 store.

static constexpr int IN    = 4096;
static constexpr int OUTW  = 4096;
static constexpr int BATCH = 2048;

__global__ __launch_bounds__(256) void prep_kernel(const float* __restrict__ x,
                                                   const float* __restrict__ luts,
                                                   uint32_t* __restrict__ xbits,
                                                   unsigned long long* __restrict__ lut_pos) {
    if (blockIdx.x < 256) {
        // ---- bit-pack x (transposed): 64 row-groups x 4 col-chunks ----
        const int g = blockIdx.x >> 2;
        const int chunk = blockIdx.x & 3;
        const int m = chunk * 1024 + threadIdx.x * 4;
        const float* xb = x + ((size_t)g * 32) * IN + m;
        uint32_t v0 = 0, v1 = 0, v2 = 0, v3 = 0;
#pragma unroll
        for (int r = 0; r < 32; ++r) {
            const float4 f = *(const float4*)(xb + (size_t)r * IN);
            v0 |= ((uint32_t)(f.x != 0.0f)) << r;
            v1 |= ((uint32_t)(f.y != 0.0f)) << r;
            v2 |= ((uint32_t)(f.z != 0.0f)) << r;
            v3 |= ((uint32_t)(f.w != 0.0f)) << r;
        }
        *(uint4*)(xbits + (size_t)g * IN + m) = make_uint4(v0, v1, v2, v3);
    } else {
        // ---- lut sign masks: 32 blocks x 4 waves x 32 rows, 4-wide pipelined ----
        const int wave = threadIdx.x >> 6;
        const int lane = threadIdx.x & 63;
        const int base = (blockIdx.x - 256) * 128 + wave * 32;
#pragma unroll
        for (int i = 0; i < 32; i += 4) {
            const float v0 = luts[(size_t)(base + i + 0) * 64 + lane];
            const float v1 = luts[(size_t)(base + i + 1) * 64 + lane];
            const float v2 = luts[(size_t)(base + i + 2) * 64 + lane];
            const float v3 = luts[(size_t)(base + i + 3) * 64 + lane];
            const unsigned long long m0 = __ballot(v0 > 0.0f);
            const unsigned long long m1 = __ballot(v1 > 0.0f);
            const unsigned long long m2 = __ballot(v2 > 0.0f);
            const unsigned long long m3 = __ballot(v3 > 0.0f);
            if (lane == 0) {
                lut_pos[base + i + 0] = m0;
                lut_pos[base + i + 1] = m1;
                lut_pos[base + i + 2] = m2;
                lut_pos[base + i + 3] = m3;
            }
        }
    }
}

__global__ __launch_bounds__(256) void lut_fwd_kernel(const int* __restrict__ mapping,
                                                      const uint32_t* __restrict__ xbits,
                                                      const unsigned long long* __restrict__ lut_pos,
                                                      float* __restrict__ out) {
    __shared__ uint32_t sbits[IN];          // 16 KB bit image for this row-group
    const int g  = blockIdx.x & 63;         // row-group
    const int cb = blockIdx.x >> 6;         // col-block (0..7), 512 cols each
    {
        const uint4* src = (const uint4*)(xbits + (size_t)g * IN);
        uint4* dst = (uint4*)sbits;
#pragma unroll
        for (int i = 0; i < 4; ++i) dst[threadIdx.x + i * 256] = src[threadIdx.x + i * 256];
    }
    __syncthreads();

    const int j = cb * 512 + threadIdx.x * 2;            // this thread: cols j, j+1
    const int4* mrow = (const int4*)(mapping + (size_t)j * 6);  // 12 ints, 16B-aligned
    const int4 q0 = mrow[0];   // c0: k0..k3
    const int4 q1 = mrow[1];   // c0: k4,k5 ; c1: k0,k1
    const int4 q2 = mrow[2];   // c1: k2..k5

    const uint32_t w00 = sbits[q0.x], w01 = sbits[q0.y], w02 = sbits[q0.z],
                   w03 = sbits[q0.w], w04 = sbits[q1.x], w05 = sbits[q1.y];
    const uint32_t w10 = sbits[q1.z], w11 = sbits[q1.w], w12 = sbits[q2.x],
                   w13 = sbits[q2.y], w14 = sbits[q2.z], w15 = sbits[q2.w];
    const ulonglong2 masks = *(const ulonglong2*)(lut_pos + j);

    float* outp = out + ((size_t)g * 32) * OUTW + j;
#pragma unroll
    for (int r = 0; r < 32; ++r) {
        const uint32_t a0 = ((w00 >> r) & 1u)        | (((w01 >> r) & 1u) << 1)
                          | (((w02 >> r) & 1u) << 2) | (((w03 >> r) & 1u) << 3)
                          | (((w04 >> r) & 1u) << 4) | (((w05 >> r) & 1u) << 5);
        const uint32_t a1 = ((w10 >> r) & 1u)        | (((w11 >> r) & 1u) << 1)
                          | (((w12 >> r) & 1u) << 2) | (((w13 >> r) & 1u) << 3)
                          | (((w14 >> r) & 1u) << 4) | (((w15 >> r) & 1u) << 5);
        float2 res;
        res.x = (float)((uint32_t)(masks.x >> a0) & 1u);
        res.y = (float)((uint32_t)(masks.y >> a1) & 1u);
        *(float2*)(outp + (size_t)r * OUTW) = res;
    }
}

// Fallback if workspace is too small: direct per-output computation.
__global__ __launch_bounds__(256) void naive_kernel(const float* __restrict__ x,
                                                    const int* __restrict__ mapping,
                                                    const float* __restrict__ luts,
                                                    float* __restrict__ out) {
    const int idx = blockIdx.x * 256 + threadIdx.x;
    if (idx >= BATCH * OUTW) return;
    const int b = idx >> 12;
    const int j = idx & (OUTW - 1);
    const float* xr = x + (size_t)b * IN;
    int addr = 0;
#pragma unroll
    for (int k = 0; k < 6; ++k) {
        addr |= ((int)(xr[mapping[j * 6 + k]] != 0.0f)) << k;
    }
    out[idx] = (luts[j * 64 + addr] > 0.0f) ? 1.0f : 0.0f;
}

extern "C" void kernel_launch(void* const* d_in, const int* in_sizes, int n_in,
                              void* d_out, int out_size, void* d_ws, size_t ws_size,
                              hipStream_t stream) {
    const float* x       = (const float*)d_in[0];
    const int*   mapping = (const int*)d_in[1];
    const float* luts    = (const float*)d_in[2];
    float* out = (float*)d_out;

    const size_t lut_pos_bytes = (size_t)OUTW * 8;            // 32 KB
    const size_t xbits_bytes   = (size_t)64 * IN * 4;         // 1 MB
    if (ws_size >= lut_pos_bytes + xbits_bytes) {
        unsigned long long* lut_pos = (unsigned long long*)d_ws;
        uint32_t* xbits = (uint32_t*)((char*)d_ws + lut_pos_bytes);
        hipLaunchKernelGGL(prep_kernel, dim3(288), dim3(256), 0, stream,
                           x, luts, xbits, lut_pos);
        hipLaunchKernelGGL(lut_fwd_kernel, dim3(512), dim3(256), 0, stream,
                           mapping, xbits, lut_pos, out);
    } else {
        hipLaunchKernelGGL(naive_kernel, dim3((BATCH * OUTW) / 256), dim3(256), 0, stream,
                           x, mapping, luts, out);
    }
}